// Round 3
// baseline (385.471 us; speedup 1.0000x reference)
//
#include <hip/hip_runtime.h>

// Problem constants
#define DIMX 2048
#define SEQ  2048
#define BATCH 2
#define NH   16
#define NKV  8
#define HD   128
#define MTOK (BATCH*SEQ)   // 4096 tokens
#define NQKV 4096          // GEMM1 output cols: 2048 Q + 1024 K + 1024 V
#define QKLD 3072          // qkv buffer stride (Q+K only; V goes to Vt)

typedef __bf16 bf16x8 __attribute__((ext_vector_type(8)));
typedef float  f32x4  __attribute__((ext_vector_type(4)));
typedef unsigned short u16x8 __attribute__((ext_vector_type(8)));
typedef unsigned short u16x4 __attribute__((ext_vector_type(4)));

__device__ __forceinline__ unsigned short f2bf(float f) {
    unsigned u = __builtin_bit_cast(unsigned, f);
    u += 0x7fffu + ((u >> 16) & 1u);            // RNE
    return (unsigned short)(u >> 16);
}
__device__ __forceinline__ float bf2f(unsigned short h) {
    unsigned u = ((unsigned)h) << 16;
    return __builtin_bit_cast(float, u);
}

__device__ __forceinline__ void gload16(const void* g, void* l) {
    __builtin_amdgcn_global_load_lds(
        (const __attribute__((address_space(1))) unsigned int*)g,
        (__attribute__((address_space(3))) unsigned int*)l, 16, 0, 0);
}

// ---------------- fp32 -> bf16 elementwise convert (8 elems/thread) ----------------
__global__ __launch_bounds__(256) void k_convert(const float* __restrict__ in,
                                                 unsigned short* __restrict__ out, int n8) {
    int i = blockIdx.x * 256 + threadIdx.x;
    if (i >= n8) return;
    f32x4 a = ((const f32x4*)in)[(size_t)i*2];
    f32x4 b = ((const f32x4*)in)[(size_t)i*2+1];
    u16x8 o;
    o[0]=f2bf(a[0]); o[1]=f2bf(a[1]); o[2]=f2bf(a[2]); o[3]=f2bf(a[3]);
    o[4]=f2bf(b[0]); o[5]=f2bf(b[1]); o[6]=f2bf(b[2]); o[7]=f2bf(b[3]);
    ((u16x8*)out)[i] = o;
}

// ---------------- fp32 KxN -> bf16 NxK transpose (64x64 tiles via LDS) ----------------
__global__ __launch_bounds__(256) void k_transpose(const float* __restrict__ W,
                                                   unsigned short* __restrict__ Wt,
                                                   int K, int N) {
    __shared__ unsigned short tile[64*65];
    int t = threadIdx.x;
    int n0 = blockIdx.x * 64, k0 = blockIdx.y * 64;
    #pragma unroll
    for (int i = 0; i < 16; ++i) {
        int idx = t + i*256, r = idx >> 6, c = idx & 63;
        tile[r*65+c] = f2bf(W[(size_t)(k0+r)*N + n0 + c]);
    }
    __syncthreads();
    #pragma unroll
    for (int i = 0; i < 16; ++i) {
        int idx = t + i*256, n = idx >> 6, k = idx & 63;
        Wt[(size_t)(n0+n)*K + k0 + k] = tile[k*65+n];
    }
}

// ---------------- bf16 GEMM, m97 structure ----------------
// MODE 0: bf16 C with ldc; blocks with col0>=3072 write V transposed to Vt.
// MODE 1: fp32 C with ldc.
template<int MODE>
__global__ __launch_bounds__(256) void k_gemm(const unsigned short* __restrict__ A,
                                              const unsigned short* __restrict__ Bt,
                                              void* __restrict__ Cv,
                                              unsigned short* __restrict__ Vt,
                                              int M, int N, int K, int ldc) {
    __shared__ unsigned short As[128*32];
    __shared__ unsigned short Bs[128*32];
    int tid = threadIdx.x;
    int wave = tid >> 6, lane = tid & 63;
    int g = lane >> 4, r16 = lane & 15;
    int row0 = blockIdx.y * 128, col0 = blockIdx.x * 128;
    int wr = wave >> 1, wc = wave & 1;
    f32x4 acc[4][4] = {};
    const unsigned short* ga = A  + (size_t)(row0 + wave*32 + (lane>>2))*K + (lane&3)*8;
    const unsigned short* gb = Bt + (size_t)(col0 + wave*32 + (lane>>2))*K + (lane&3)*8;
    unsigned short* lA = As + wave*1024;
    unsigned short* lB = Bs + wave*1024;
    for (int k0 = 0; k0 < K; k0 += 32) {
        __syncthreads();
        gload16(ga + k0,                 lA);
        gload16(ga + k0 + (size_t)16*K, lA + 512);
        gload16(gb + k0,                 lB);
        gload16(gb + k0 + (size_t)16*K, lB + 512);
        __syncthreads();
        bf16x8 af[4], bfr[4];
        #pragma unroll
        for (int mi = 0; mi < 4; ++mi)
            af[mi] = *(const bf16x8*)&As[(wr*64 + mi*16 + r16)*32 + g*8];
        #pragma unroll
        for (int ni = 0; ni < 4; ++ni)
            bfr[ni] = *(const bf16x8*)&Bs[(wc*64 + ni*16 + r16)*32 + g*8];
        #pragma unroll
        for (int mi = 0; mi < 4; ++mi)
            #pragma unroll
            for (int ni = 0; ni < 4; ++ni)
                acc[mi][ni] = __builtin_amdgcn_mfma_f32_16x16x32_bf16(af[mi], bfr[ni], acc[mi][ni], 0, 0, 0);
    }
    if (MODE == 0 && col0 >= 3072) {
        // V columns: store transposed as Vt[b][kvh][d][s], packed 4 bf16 along s
        #pragma unroll
        for (int mi = 0; mi < 4; ++mi)
            #pragma unroll
            for (int ni = 0; ni < 4; ++ni) {
                int vcol = col0 + wc*64 + ni*16 + r16 - 3072;
                int d = vcol & 127, kh = vcol >> 7;
                int row = row0 + wr*64 + mi*16 + g*4;
                int b = row >> 11, s = row & (SEQ-1);
                u16x4 pk;
                #pragma unroll
                for (int rr = 0; rr < 4; ++rr) pk[rr] = f2bf(acc[mi][ni][rr]);
                *(u16x4*)&Vt[((size_t)(b*NKV + kh)*HD + d)*SEQ + s] = pk;
            }
    } else {
        #pragma unroll
        for (int mi = 0; mi < 4; ++mi)
            #pragma unroll
            for (int ni = 0; ni < 4; ++ni)
                #pragma unroll
                for (int rr = 0; rr < 4; ++rr) {
                    int row = row0 + wr*64 + mi*16 + g*4 + rr;
                    int col = col0 + wc*64 + ni*16 + r16;
                    float v = acc[mi][ni][rr];
                    if (MODE == 1) ((float*)Cv)[(size_t)row*ldc + col] = v;
                    else ((unsigned short*)Cv)[(size_t)row*ldc + col] = f2bf(v);
                }
    }
}

// ---------------- RoPE in place on Q and K columns of the qkv buffer (ld=3072) ----------------
__global__ __launch_bounds__(256) void k_rope(unsigned short* __restrict__ qkv) {
    int tid = blockIdx.x * 256 + threadIdx.x;   // MTOK*(NH+NKV)*64 threads
    int i    = tid & 63;                        // rotation pair index
    int rest = tid >> 6;
    int head = rest % (NH + NKV);
    int tok  = rest / (NH + NKV);
    int pos  = tok & (SEQ - 1);
    size_t base = (size_t)tok * QKLD + head*HD;
    float x1 = bf2f(qkv[base + i]);
    float x2 = bf2f(qkv[base + i + 64]);
    float inv = exp2f(-0.20762050593046014f * (float)i);   // 10000^(-i/64)
    float ang = (float)pos * inv;
    float s, c;
    sincosf(ang, &s, &c);
    qkv[base + i]      = f2bf(x1*c - x2*s);
    qkv[base + i + 64] = f2bf(x2*c + x1*s);
}

// ---------------- causal GQA flash attention, barrier-free global-direct design ----------------
// 1D grid of 512 blocks, 4 waves/block; wave independently owns 32 q-rows (2 x 16-row halves).
// K/V fragments read straight from global (L1/L2-served); only P round-trips per-wave LDS.
// S^T = mfma(K,Q): lane q=lane&15, kv=(lane>>4)*4+reg. O^T = mfma(Vt,P): lane q=lane&15, d rows.
__global__ __launch_bounds__(256, 2) void k_attn(const unsigned short* __restrict__ qkv,
                                                 const unsigned short* __restrict__ Vt,
                                                 unsigned short* __restrict__ attn_out) {
    __shared__ __align__(16) unsigned short Pl[4][2][1024];  // [wave][half][16q x 64kv] swizzled
    int bid = blockIdx.x;
    // XCD-grouped bh (4 bh per XCD -> 4MB L2 working set) + CU-paired complementary qt
    int xcd = bid & 7, slot = bid >> 3;
    int bh  = xcd * 4 + (slot >> 4);
    int xx  = slot & 15;
    int qt  = ((slot >> 5) & 1) ? xx : 15 - xx;
    int b = bh >> 4, h = bh & 15;
    int kvh = h >> 1;
    int tid = threadIdx.x, wave = tid >> 6, lane = tid & 63;
    int g = lane >> 4, r16 = lane & 15;
    int q0w = qt * 128 + wave * 32;
    int qr0 = q0w + r16;
    const unsigned short* qbase = qkv + (size_t)(b * SEQ) * QKLD;
    const char* kbase = (const char*)(qbase + DIMX + kvh * HD);                 // + row*QKLD*2
    const char* vbase = (const char*)(Vt + ((size_t)(b * NKV + kvh) * HD) * SEQ); // + d*SEQ*2

    // Q fragments for both 16-row halves
    bf16x8 qf[2][4];
    #pragma unroll
    for (int hf = 0; hf < 2; ++hf)
        #pragma unroll
        for (int dc = 0; dc < 4; ++dc)
            qf[hf][dc] = *(const bf16x8*)(qbase + (size_t)(qr0 + hf*16) * QKLD + h*HD + dc*32 + g*8);

    f32x4 acc[2][8] = {};
    float mrow[2] = {-1e30f, -1e30f};
    float lrow[2] = {0.f, 0.f};
    const float SC = 0.08838834764831845f * 1.4426950408889634f;  // rsqrt(128)*log2(e)
    char* Pw[2] = { (char*)&Pl[wave][0][0], (char*)&Pl[wave][1][0] };

    int ntiles = ((q0w + 31) >> 6) + 1;
    for (int it = 0; it < ntiles; ++it) {
        int kv0 = it * 64;
        const char* krow = kbase + (size_t)kv0 * (QKLD * 2);
        // S^T = K . Q^T, K-frags direct from global
        f32x4 s[2][4];
        #pragma unroll
        for (int hf = 0; hf < 2; ++hf)
            #pragma unroll
            for (int nt = 0; nt < 4; ++nt) s[hf][nt] = (f32x4){0.f,0.f,0.f,0.f};
        #pragma unroll
        for (int nt = 0; nt < 4; ++nt) {
            bf16x8 kf[4];
            #pragma unroll
            for (int dc = 0; dc < 4; ++dc)
                kf[dc] = *(const bf16x8*)(krow + (size_t)(nt*16 + r16)*(QKLD*2) + dc*64 + g*16);
            __builtin_amdgcn_s_setprio(1);
            #pragma unroll
            for (int dc = 0; dc < 4; ++dc) {
                s[0][nt] = __builtin_amdgcn_mfma_f32_16x16x32_bf16(kf[dc], qf[0][dc], s[0][nt], 0, 0, 0);
                s[1][nt] = __builtin_amdgcn_mfma_f32_16x16x32_bf16(kf[dc], qf[1][dc], s[1][nt], 0, 0, 0);
            }
            __builtin_amdgcn_s_setprio(0);
        }
        // softmax per half (lane-local rows: q=r16, 16 kv entries across regs)
        #pragma unroll
        for (int hf = 0; hf < 2; ++hf) {
            int qr = qr0 + hf * 16;
            float mt = -1e30f;
            if (kv0 + 63 <= q0w + hf*16) {          // wave-uniform: tile fully unmasked
                #pragma unroll
                for (int nt = 0; nt < 4; ++nt)
                    #pragma unroll
                    for (int rr = 0; rr < 4; ++rr) {
                        float v = s[hf][nt][rr] * SC;
                        s[hf][nt][rr] = v; mt = fmaxf(mt, v);
                    }
            } else {
                #pragma unroll
                for (int nt = 0; nt < 4; ++nt)
                    #pragma unroll
                    for (int rr = 0; rr < 4; ++rr) {
                        int kv = kv0 + nt*16 + g*4 + rr;
                        float v = (kv <= qr) ? s[hf][nt][rr] * SC : -1e30f;
                        s[hf][nt][rr] = v; mt = fmaxf(mt, v);
                    }
            }
            mt = fmaxf(mt, __shfl_xor(mt, 16, 64));
            mt = fmaxf(mt, __shfl_xor(mt, 32, 64));
            float mn = fmaxf(mrow[hf], mt);
            float corr = exp2f(mrow[hf] - mn);
            mrow[hf] = mn;
            float rs = 0.f;
            #pragma unroll
            for (int nt = 0; nt < 4; ++nt)
                #pragma unroll
                for (int hh = 0; hh < 2; ++hh) {
                    float p0 = exp2f(s[hf][nt][2*hh]   - mn);
                    float p1 = exp2f(s[hf][nt][2*hh+1] - mn);
                    rs += p0 + p1;
                    unsigned pkw = (unsigned)f2bf(p0) | ((unsigned)f2bf(p1) << 16);
                    unsigned o = r16*128 + nt*32 + g*8 + hh*4;
                    *(unsigned*)(Pw[hf] + (o ^ ((r16 & 7) << 4))) = pkw;
                }
            rs += __shfl_xor(rs, 16, 64);
            rs += __shfl_xor(rs, 32, 64);
            lrow[hf] = lrow[hf] * corr + rs;
            #pragma unroll
            for (int dt = 0; dt < 8; ++dt)
                #pragma unroll
                for (int rr = 0; rr < 4; ++rr)
                    acc[hf][dt][rr] *= corr;
        }
        // P back as B-frags (per-wave LDS, no barrier needed)
        bf16x8 pf[2][2];
        #pragma unroll
        for (int hf = 0; hf < 2; ++hf)
            #pragma unroll
            for (int kvc = 0; kvc < 2; ++kvc) {
                unsigned o = r16*128 + kvc*64 + g*16;
                pf[hf][kvc] = *(const bf16x8*)(Pw[hf] + (o ^ ((r16 & 7) << 4)));
            }
        // O^T += Vt . P, V-frags direct from global
        const char* vrow = vbase + (size_t)kv0 * 2;
        #pragma unroll
        for (int dt = 0; dt < 8; ++dt) {
            const char* vr = vrow + (size_t)(dt*16 + r16) * (SEQ*2) + g*16;
            bf16x8 vf0 = *(const bf16x8*)(vr);
            bf16x8 vf1 = *(const bf16x8*)(vr + 64);
            __builtin_amdgcn_s_setprio(1);
            acc[0][dt] = __builtin_amdgcn_mfma_f32_16x16x32_bf16(vf0, pf[0][0], acc[0][dt], 0, 0, 0);
            acc[0][dt] = __builtin_amdgcn_mfma_f32_16x16x32_bf16(vf1, pf[0][1], acc[0][dt], 0, 0, 0);
            acc[1][dt] = __builtin_amdgcn_mfma_f32_16x16x32_bf16(vf0, pf[1][0], acc[1][dt], 0, 0, 0);
            acc[1][dt] = __builtin_amdgcn_mfma_f32_16x16x32_bf16(vf1, pf[1][1], acc[1][dt], 0, 0, 0);
            __builtin_amdgcn_s_setprio(0);
        }
    }
    // epilogue: normalize, write bf16 (4 consecutive d per lane -> 8B stores)
    #pragma unroll
    for (int hf = 0; hf < 2; ++hf) {
        float inv = 1.0f / lrow[hf];
        #pragma unroll
        for (int dt = 0; dt < 8; ++dt) {
            u16x4 o4;
            #pragma unroll
            for (int rr = 0; rr < 4; ++rr) o4[rr] = f2bf(acc[hf][dt][rr] * inv);
            *(u16x4*)&attn_out[(size_t)(b*SEQ + qr0 + hf*16)*DIMX + h*HD + dt*16 + g*4] = o4;
        }
    }
}

extern "C" void kernel_launch(void* const* d_in, const int* in_sizes, int n_in,
                              void* d_out, int out_size, void* d_ws, size_t ws_size,
                              hipStream_t stream) {
    const float* x  = (const float*)d_in[0];
    const float* Wq = (const float*)d_in[1];
    const float* Wk = (const float*)d_in[2];
    const float* Wv = (const float*)d_in[3];
    const float* Wo = (const float*)d_in[4];

    // ws layout (all u16), total 92.3 MB
    unsigned short* xb   = (unsigned short*)d_ws;                 // 4096x2048
    unsigned short* Wtq  = xb  + (size_t)MTOK*DIMX;               // 4096x2048 (QKV weights, NxK)
    unsigned short* Wto  = Wtq + (size_t)NQKV*DIMX;               // 2048x2048 (Wo^T)
    unsigned short* qkv  = Wto + (size_t)DIMX*DIMX;               // 4096x3072 (Q|K, ld 3072)
    unsigned short* aout = qkv + (size_t)MTOK*QKLD;               // 4096x2048
    unsigned short* Vt   = aout + (size_t)MTOK*DIMX;              // [2][8][128][2048]

    k_convert<<<(MTOK*DIMX/8 + 255)/256, 256, 0, stream>>>(x, xb, MTOK*DIMX/8);

    dim3 tg32(DIMX/64, DIMX/64);
    dim3 tg16(1024/64, DIMX/64);
    k_transpose<<<tg32, 256, 0, stream>>>(Wq, Wtq,                         DIMX, DIMX);
    k_transpose<<<tg16, 256, 0, stream>>>(Wk, Wtq + (size_t)2048*DIMX,     DIMX, 1024);
    k_transpose<<<tg16, 256, 0, stream>>>(Wv, Wtq + (size_t)3072*DIMX,     DIMX, 1024);
    k_transpose<<<tg32, 256, 0, stream>>>(Wo, Wto,                         DIMX, DIMX);

    dim3 g1(NQKV/128, MTOK/128);
    k_gemm<0><<<g1, 256, 0, stream>>>(xb, Wtq, qkv, Vt, MTOK, NQKV, DIMX, QKLD);

    k_rope<<<(MTOK*(NH+NKV)*64)/256, 256, 0, stream>>>(qkv);

    k_attn<<<512, 256, 0, stream>>>(qkv, Vt, aout);

    dim3 g2(DIMX/128, MTOK/128);
    k_gemm<1><<<g2, 256, 0, stream>>>(aout, Wto, (float*)d_out, nullptr, MTOK, DIMX, DIMX, DIMX);
}

// Round 4
// 277.282 us; speedup vs baseline: 1.3902x; 1.3902x over previous
//
#include <hip/hip_runtime.h>

// Problem constants
#define DIMX 2048
#define SEQ  2048
#define BATCH 2
#define NH   16
#define NKV  8
#define HD   128
#define MTOK (BATCH*SEQ)   // 4096 tokens
#define NQKV 4096          // GEMM1 output cols: 2048 Q + 1024 K + 1024 V
#define QKLD 3072          // qkv buffer stride (Q+K only; V goes to Vt)

typedef __bf16 bf16x8 __attribute__((ext_vector_type(8)));
typedef float  f32x4  __attribute__((ext_vector_type(4)));
typedef float  f32x16 __attribute__((ext_vector_type(16)));
typedef unsigned short u16x8 __attribute__((ext_vector_type(8)));
typedef unsigned short u16x4 __attribute__((ext_vector_type(4)));
typedef unsigned int   u32x4 __attribute__((ext_vector_type(4)));

__device__ __forceinline__ unsigned short f2bf(float f) {
    unsigned u = __builtin_bit_cast(unsigned, f);
    u += 0x7fffu + ((u >> 16) & 1u);            // RNE
    return (unsigned short)(u >> 16);
}
__device__ __forceinline__ float bf2f(unsigned short h) {
    unsigned u = ((unsigned)h) << 16;
    return __builtin_bit_cast(float, u);
}

__device__ __forceinline__ void gload16(const void* g, void* l) {
    __builtin_amdgcn_global_load_lds(
        (const __attribute__((address_space(1))) unsigned int*)g,
        (__attribute__((address_space(3))) unsigned int*)l, 16, 0, 0);
}

// ---------------- fp32 -> bf16 elementwise convert (8 elems/thread) ----------------
__global__ __launch_bounds__(256) void k_convert(const float* __restrict__ in,
                                                 unsigned short* __restrict__ out, int n8) {
    int i = blockIdx.x * 256 + threadIdx.x;
    if (i >= n8) return;
    f32x4 a = ((const f32x4*)in)[(size_t)i*2];
    f32x4 b = ((const f32x4*)in)[(size_t)i*2+1];
    u16x8 o;
    o[0]=f2bf(a[0]); o[1]=f2bf(a[1]); o[2]=f2bf(a[2]); o[3]=f2bf(a[3]);
    o[4]=f2bf(b[0]); o[5]=f2bf(b[1]); o[6]=f2bf(b[2]); o[7]=f2bf(b[3]);
    ((u16x8*)out)[i] = o;
}

// ---------------- fp32 KxN -> bf16 NxK transpose (64x64 tiles via LDS) ----------------
__global__ __launch_bounds__(256) void k_transpose(const float* __restrict__ W,
                                                   unsigned short* __restrict__ Wt,
                                                   int K, int N) {
    __shared__ unsigned short tile[64*65];
    int t = threadIdx.x;
    int n0 = blockIdx.x * 64, k0 = blockIdx.y * 64;
    #pragma unroll
    for (int i = 0; i < 16; ++i) {
        int idx = t + i*256, r = idx >> 6, c = idx & 63;
        tile[r*65+c] = f2bf(W[(size_t)(k0+r)*N + n0 + c]);
    }
    __syncthreads();
    #pragma unroll
    for (int i = 0; i < 16; ++i) {
        int idx = t + i*256, n = idx >> 6, k = idx & 63;
        Wt[(size_t)(n0+n)*K + k0 + k] = tile[k*65+n];
    }
}

// ---------------- bf16 GEMM, m97 structure ----------------
// MODE 0: bf16 C with ldc; blocks with col0>=3072 write V transposed to Vt.
// MODE 1: fp32 C with ldc.
template<int MODE>
__global__ __launch_bounds__(256) void k_gemm(const unsigned short* __restrict__ A,
                                              const unsigned short* __restrict__ Bt,
                                              void* __restrict__ Cv,
                                              unsigned short* __restrict__ Vt,
                                              int M, int N, int K, int ldc) {
    __shared__ unsigned short As[128*32];
    __shared__ unsigned short Bs[128*32];
    int tid = threadIdx.x;
    int wave = tid >> 6, lane = tid & 63;
    int g = lane >> 4, r16 = lane & 15;
    int row0 = blockIdx.y * 128, col0 = blockIdx.x * 128;
    int wr = wave >> 1, wc = wave & 1;
    f32x4 acc[4][4] = {};
    const unsigned short* ga = A  + (size_t)(row0 + wave*32 + (lane>>2))*K + (lane&3)*8;
    const unsigned short* gb = Bt + (size_t)(col0 + wave*32 + (lane>>2))*K + (lane&3)*8;
    unsigned short* lA = As + wave*1024;
    unsigned short* lB = Bs + wave*1024;
    for (int k0 = 0; k0 < K; k0 += 32) {
        __syncthreads();
        gload16(ga + k0,                 lA);
        gload16(ga + k0 + (size_t)16*K, lA + 512);
        gload16(gb + k0,                 lB);
        gload16(gb + k0 + (size_t)16*K, lB + 512);
        __syncthreads();
        bf16x8 af[4], bfr[4];
        #pragma unroll
        for (int mi = 0; mi < 4; ++mi)
            af[mi] = *(const bf16x8*)&As[(wr*64 + mi*16 + r16)*32 + g*8];
        #pragma unroll
        for (int ni = 0; ni < 4; ++ni)
            bfr[ni] = *(const bf16x8*)&Bs[(wc*64 + ni*16 + r16)*32 + g*8];
        #pragma unroll
        for (int mi = 0; mi < 4; ++mi)
            #pragma unroll
            for (int ni = 0; ni < 4; ++ni)
                acc[mi][ni] = __builtin_amdgcn_mfma_f32_16x16x32_bf16(af[mi], bfr[ni], acc[mi][ni], 0, 0, 0);
    }
    if (MODE == 0 && col0 >= 3072) {
        // V columns: store transposed as Vt[b][kvh][d][s], packed 4 bf16 along s
        #pragma unroll
        for (int mi = 0; mi < 4; ++mi)
            #pragma unroll
            for (int ni = 0; ni < 4; ++ni) {
                int vcol = col0 + wc*64 + ni*16 + r16 - 3072;
                int d = vcol & 127, kh = vcol >> 7;
                int row = row0 + wr*64 + mi*16 + g*4;
                int b = row >> 11, s = row & (SEQ-1);
                u16x4 pk;
                #pragma unroll
                for (int rr = 0; rr < 4; ++rr) pk[rr] = f2bf(acc[mi][ni][rr]);
                *(u16x4*)&Vt[((size_t)(b*NKV + kh)*HD + d)*SEQ + s] = pk;
            }
    } else {
        #pragma unroll
        for (int mi = 0; mi < 4; ++mi)
            #pragma unroll
            for (int ni = 0; ni < 4; ++ni)
                #pragma unroll
                for (int rr = 0; rr < 4; ++rr) {
                    int row = row0 + wr*64 + mi*16 + g*4 + rr;
                    int col = col0 + wc*64 + ni*16 + r16;
                    float v = acc[mi][ni][rr];
                    if (MODE == 1) ((float*)Cv)[(size_t)row*ldc + col] = v;
                    else ((unsigned short*)Cv)[(size_t)row*ldc + col] = f2bf(v);
                }
    }
}

// ---------------- RoPE in place on Q and K columns of the qkv buffer (ld=3072) ----------------
__global__ __launch_bounds__(256) void k_rope(unsigned short* __restrict__ qkv) {
    int tid = blockIdx.x * 256 + threadIdx.x;   // MTOK*(NH+NKV)*64 threads
    int i    = tid & 63;                        // rotation pair index
    int rest = tid >> 6;
    int head = rest % (NH + NKV);
    int tok  = rest / (NH + NKV);
    int pos  = tok & (SEQ - 1);
    size_t base = (size_t)tok * QKLD + head*HD;
    float x1 = bf2f(qkv[base + i]);
    float x2 = bf2f(qkv[base + i + 64]);
    float inv = exp2f(-0.20762050593046014f * (float)i);   // 10000^(-i/64)
    float ang = (float)pos * inv;
    float s, c;
    sincosf(ang, &s, &c);
    qkv[base + i]      = f2bf(x1*c - x2*s);
    qkv[base + i + 64] = f2bf(x2*c + x1*s);
}

// ---------------- causal GQA flash attention, 32x32 MFMA + in-register softmax ----------------
// Grid: 512 blocks x 256 threads (4 waves). Wave owns 32 q-rows; block = 128 q-rows. KVBLK=64.
// S^T = mfma32(K, Q): lane q = lane&31, kv rows = (r&3)+8*(r>>2)+4*hi (+32t). Softmax lane-local.
// P built in-register (cvt_pk_bf16 + permlane32_swap). O^T = mfma32(Vt, P).
// K/V double-buffered in LDS, XOR-swizzled (byte ^= (row&7)<<4), source pre-swizzled for gload_lds.
__global__ __launch_bounds__(256, 2) void k_attn(const unsigned short* __restrict__ qkv,
                                                 const unsigned short* __restrict__ Vt,
                                                 unsigned short* __restrict__ attn_out) {
    __shared__ __align__(16) char KsB[2][16384];   // [kv 64][d 128] bf16, 256B rows
    __shared__ __align__(16) char VsB[2][16384];   // [d 128][kv 64] bf16, 128B rows
    int bid = blockIdx.x;
    int xcd = bid & 7, slot = bid >> 3;            // 64 slots per XCD
    int bh  = xcd * 4 + (slot >> 4);               // 4 bh per XCD (L2 locality)
    int xx  = slot & 15;
    int qt  = (slot & 32) ? (15 - xx) : xx;        // complementary qt pairing for causal balance
    int b = bh >> 4, h = bh & 15;
    int kvh = h >> 1;
    int tid = threadIdx.x, wave = tid >> 6, lane = tid & 63;
    int l31 = lane & 31, hi = lane >> 5;
    int q0w = qt * 128 + wave * 32;
    int qg  = q0w + l31;                           // this lane's q row
    const unsigned short* qbase = qkv + (size_t)(b * SEQ) * QKLD;
    const char* kbase = (const char*)(qbase + DIMX + kvh * HD);                  // + row*QKLD*2
    const char* vbase = (const char*)(Vt + ((size_t)(b * NKV + kvh) * HD) * SEQ); // + d*SEQ*2

    // Q B-frags: lane holds Q[qg][d = 16s + 8hi + j]
    bf16x8 qf[8];
    {
        const unsigned short* qrow = qbase + (size_t)qg * QKLD + h * HD;
        #pragma unroll
        for (int s2 = 0; s2 < 8; ++s2)
            qf[s2] = *(const bf16x8*)(qrow + s2*16 + hi*8);
    }

    f32x16 acc[4] = {};                            // O^T: d = 32dt + (r&3)+8(r>>2)+4hi, q = l31
    float mrow = -1e30f, lrow = 0.f;
    const float SC = 0.08838834764831845f * 1.4426950408889634f;  // rsqrt(128)*log2(e)

    auto STAGE = [&](int bsel, int it) {
        int kv0 = it * 64;
        char* KL = KsB[bsel];
        char* VL = VsB[bsel];
        #pragma unroll
        for (int p = 0; p < 4; ++p) {
            int c = wave*4 + p;
            {   // K chunk: LDS[o] = K[o>>8][(o&255) ^ ((row&7)<<4)]
                int row  = c*4 + (lane >> 4);
                int colb = ((lane & 15) * 16) ^ ((row & 7) << 4);
                gload16(kbase + (size_t)(kv0 + row) * (QKLD*2) + colb, KL + c*1024);
            }
            {   // V chunk: LDS[o] = Vt[o>>7][(o&127) ^ ((d&7)<<4)]
                int d    = c*8 + (lane >> 3);
                int colb = ((lane & 7) * 16) ^ ((d & 7) << 4);
                gload16(vbase + (size_t)d * (SEQ*2) + (size_t)kv0*2 + colb, VL + c*1024);
            }
        }
    };

    int nt = 2*qt + 2;
    STAGE(0, 0);
    asm volatile("s_waitcnt vmcnt(0)" ::: "memory");
    __syncthreads();

    for (int it = 0; it < nt; ++it) {
        int bsel = it & 1;
        int kv0 = it * 64;
        if (it + 1 < nt) STAGE((it+1) & 1, it + 1);     // issue next-tile loads (overlap compute)
        if (kv0 <= q0w + 31) {
            const char* KL = KsB[bsel];
            const char* VL = VsB[bsel];
            // ---- S^T = K . Q^T ----
            f32x16 st[2] = {};
            __builtin_amdgcn_s_setprio(1);
            #pragma unroll
            for (int t = 0; t < 2; ++t) {
                int row = t*32 + l31;
                const char* kr = KL + row*256;
                unsigned sw = (unsigned)((row & 7) << 4);
                #pragma unroll
                for (int s2 = 0; s2 < 8; ++s2) {
                    bf16x8 kf = *(const bf16x8*)(kr + (((unsigned)(s2*32 + hi*16)) ^ sw));
                    st[t] = __builtin_amdgcn_mfma_f32_32x32x16_bf16(kf, qf[s2], st[t], 0, 0, 0);
                }
            }
            __builtin_amdgcn_s_setprio(0);
            // ---- scale + causal mask + lane-local max ----
            float mt = -1e30f;
            if (kv0 + 63 <= q0w) {
                #pragma unroll
                for (int t = 0; t < 2; ++t)
                    #pragma unroll
                    for (int r = 0; r < 16; ++r) {
                        float v = st[t][r] * SC;
                        st[t][r] = v; mt = fmaxf(mt, v);
                    }
            } else {
                #pragma unroll
                for (int t = 0; t < 2; ++t)
                    #pragma unroll
                    for (int r = 0; r < 16; ++r) {
                        int kv = kv0 + t*32 + (r & 3) + 8*(r >> 2) + 4*hi;
                        float v = (kv <= qg) ? st[t][r] * SC : -1e30f;
                        st[t][r] = v; mt = fmaxf(mt, v);
                    }
            }
            mt = fmaxf(mt, __shfl_xor(mt, 32, 64));
            // ---- defer-max online softmax (T13, THR=8) ----
            if (!__all(mt - mrow <= 8.0f)) {
                float mn = fmaxf(mrow, mt);
                float corr = exp2f(mrow - mn);
                mrow = mn;
                lrow *= corr;
                #pragma unroll
                for (int dt = 0; dt < 4; ++dt)
                    #pragma unroll
                    for (int r = 0; r < 16; ++r) acc[dt][r] *= corr;
            }
            float rs = 0.f;
            #pragma unroll
            for (int t = 0; t < 2; ++t)
                #pragma unroll
                for (int r = 0; r < 16; ++r) {
                    float p = exp2f(st[t][r] - mrow);
                    st[t][r] = p; rs += p;
                }
            rs += __shfl_xor(rs, 32, 64);
            lrow += rs;
            // ---- P in-register (cvt_pk + permlane32_swap) + PV ----
            #pragma unroll
            for (int t = 0; t < 2; ++t)
                #pragma unroll
                for (int ks = 0; ks < 2; ++ks) {
                    int rb = ks * 8;
                    float p0 = st[t][rb+0], p1 = st[t][rb+1], p2 = st[t][rb+2], p3 = st[t][rb+3];
                    float p4 = st[t][rb+4], p5 = st[t][rb+5], p6 = st[t][rb+6], p7 = st[t][rb+7];
                    unsigned w0, w1, w2, w3;
                    asm("v_cvt_pk_bf16_f32 %0, %1, %2" : "=v"(w0) : "v"(p0), "v"(p1));
                    asm("v_cvt_pk_bf16_f32 %0, %1, %2" : "=v"(w1) : "v"(p2), "v"(p3));
                    asm("v_cvt_pk_bf16_f32 %0, %1, %2" : "=v"(w2) : "v"(p4), "v"(p5));
                    asm("v_cvt_pk_bf16_f32 %0, %1, %2" : "=v"(w3) : "v"(p6), "v"(p7));
                    asm("v_permlane32_swap_b32 %0, %1" : "+v"(w0), "+v"(w2));
                    asm("v_permlane32_swap_b32 %0, %1" : "+v"(w1), "+v"(w3));
                    u32x4 pu = {w0, w1, w2, w3};
                    bf16x8 pfrag = __builtin_bit_cast(bf16x8, pu);
                    int ks4 = t*2 + ks;
                    __builtin_amdgcn_s_setprio(1);
                    #pragma unroll
                    for (int dt = 0; dt < 4; ++dt) {
                        int d = dt*32 + l31;
                        bf16x8 vf = *(const bf16x8*)(VL + d*128 +
                                     (((unsigned)(ks4*32 + hi*16)) ^ ((unsigned)((d & 7) << 4))));
                        acc[dt] = __builtin_amdgcn_mfma_f32_32x32x16_bf16(vf, pfrag, acc[dt], 0, 0, 0);
                    }
                    __builtin_amdgcn_s_setprio(0);
                }
        }
        asm volatile("s_waitcnt vmcnt(0)" ::: "memory");
        __syncthreads();
    }

    // ---- epilogue: normalize (lane-local), write bf16, 8B stores ----
    float inv = 1.0f / lrow;
    #pragma unroll
    for (int dt = 0; dt < 4; ++dt)
        #pragma unroll
        for (int qd = 0; qd < 4; ++qd) {
            u16x4 o4;
            #pragma unroll
            for (int j = 0; j < 4; ++j) o4[j] = f2bf(acc[dt][qd*4 + j] * inv);
            int d0 = dt*32 + qd*8 + hi*4;
            *(u16x4*)&attn_out[(size_t)(b*SEQ + qg)*DIMX + h*HD + d0] = o4;
        }
}

extern "C" void kernel_launch(void* const* d_in, const int* in_sizes, int n_in,
                              void* d_out, int out_size, void* d_ws, size_t ws_size,
                              hipStream_t stream) {
    const float* x  = (const float*)d_in[0];
    const float* Wq = (const float*)d_in[1];
    const float* Wk = (const float*)d_in[2];
    const float* Wv = (const float*)d_in[3];
    const float* Wo = (const float*)d_in[4];

    // ws layout (all u16), total 92.3 MB
    unsigned short* xb   = (unsigned short*)d_ws;                 // 4096x2048
    unsigned short* Wtq  = xb  + (size_t)MTOK*DIMX;               // 4096x2048 (QKV weights, NxK)
    unsigned short* Wto  = Wtq + (size_t)NQKV*DIMX;               // 2048x2048 (Wo^T)
    unsigned short* qkv  = Wto + (size_t)DIMX*DIMX;               // 4096x3072 (Q|K, ld 3072)
    unsigned short* aout = qkv + (size_t)MTOK*QKLD;               // 4096x2048
    unsigned short* Vt   = aout + (size_t)MTOK*DIMX;              // [2][8][128][2048]

    k_convert<<<(MTOK*DIMX/8 + 255)/256, 256, 0, stream>>>(x, xb, MTOK*DIMX/8);

    dim3 tg32(DIMX/64, DIMX/64);
    dim3 tg16(1024/64, DIMX/64);
    k_transpose<<<tg32, 256, 0, stream>>>(Wq, Wtq,                         DIMX, DIMX);
    k_transpose<<<tg16, 256, 0, stream>>>(Wk, Wtq + (size_t)2048*DIMX,     DIMX, 1024);
    k_transpose<<<tg16, 256, 0, stream>>>(Wv, Wtq + (size_t)3072*DIMX,     DIMX, 1024);
    k_transpose<<<tg32, 256, 0, stream>>>(Wo, Wto,                         DIMX, DIMX);

    dim3 g1(NQKV/128, MTOK/128);
    k_gemm<0><<<g1, 256, 0, stream>>>(xb, Wtq, qkv, Vt, MTOK, NQKV, DIMX, QKLD);

    k_rope<<<(MTOK*(NH+NKV)*64)/256, 256, 0, stream>>>(qkv);

    k_attn<<<512, 256, 0, stream>>>(qkv, Vt, aout);

    dim3 g2(DIMX/128, MTOK/128);
    k_gemm<1><<<g2, 256, 0, stream>>>(aout, Wto, (float*)d_out, nullptr, MTOK, DIMX, DIMX, DIMX);
}

// Round 5
// 224.750 us; speedup vs baseline: 1.7151x; 1.2337x over previous
//
#include <hip/hip_runtime.h>

// Problem constants
#define DIMX 2048
#define SEQ  2048
#define BATCH 2
#define NH   16
#define NKV  8
#define HD   128
#define MTOK (BATCH*SEQ)   // 4096 tokens
#define NQKV 4096          // GEMM1 output cols: 2048 Q + 1024 K + 1024 V
#define QKLD 3072          // qkv buffer stride (Q+K only; V goes to Vt)

typedef __bf16 bf16x8 __attribute__((ext_vector_type(8)));
typedef float  f32x4  __attribute__((ext_vector_type(4)));
typedef float  f32x16 __attribute__((ext_vector_type(16)));
typedef unsigned short u16x8 __attribute__((ext_vector_type(8)));
typedef unsigned short u16x4 __attribute__((ext_vector_type(4)));
typedef unsigned int   u32x4 __attribute__((ext_vector_type(4)));

__device__ __forceinline__ unsigned short f2bf(float f) {
    unsigned u = __builtin_bit_cast(unsigned, f);
    u += 0x7fffu + ((u >> 16) & 1u);            // RNE
    return (unsigned short)(u >> 16);
}
__device__ __forceinline__ float bf2f(unsigned short h) {
    unsigned u = ((unsigned)h) << 16;
    return __builtin_bit_cast(float, u);
}

__device__ __forceinline__ void gload16(const void* g, void* l) {
    __builtin_amdgcn_global_load_lds(
        (const __attribute__((address_space(1))) unsigned int*)g,
        (__attribute__((address_space(3))) unsigned int*)l, 16, 0, 0);
}

// ---------------- fp32 -> bf16 elementwise convert (8 elems/thread) ----------------
__global__ __launch_bounds__(256) void k_convert(const float* __restrict__ in,
                                                 unsigned short* __restrict__ out, int n8) {
    int i = blockIdx.x * 256 + threadIdx.x;
    if (i >= n8) return;
    f32x4 a = ((const f32x4*)in)[(size_t)i*2];
    f32x4 b = ((const f32x4*)in)[(size_t)i*2+1];
    u16x8 o;
    o[0]=f2bf(a[0]); o[1]=f2bf(a[1]); o[2]=f2bf(a[2]); o[3]=f2bf(a[3]);
    o[4]=f2bf(b[0]); o[5]=f2bf(b[1]); o[6]=f2bf(b[2]); o[7]=f2bf(b[3]);
    ((u16x8*)out)[i] = o;
}

// ---------------- fp32 KxN -> bf16 NxK transpose (64x64 tiles via LDS) ----------------
__global__ __launch_bounds__(256) void k_transpose(const float* __restrict__ W,
                                                   unsigned short* __restrict__ Wt,
                                                   int K, int N) {
    __shared__ unsigned short tile[64*65];
    int t = threadIdx.x;
    int n0 = blockIdx.x * 64, k0 = blockIdx.y * 64;
    #pragma unroll
    for (int i = 0; i < 16; ++i) {
        int idx = t + i*256, r = idx >> 6, c = idx & 63;
        tile[r*65+c] = f2bf(W[(size_t)(k0+r)*N + n0 + c]);
    }
    __syncthreads();
    #pragma unroll
    for (int i = 0; i < 16; ++i) {
        int idx = t + i*256, n = idx >> 6, k = idx & 63;
        Wt[(size_t)(n0+n)*K + k0 + k] = tile[k*65+n];
    }
}

// ---------------- 256-wide bf16 GEMM: BMx(NREP*64) tile, BK=64, 8 waves (2Mx4N) ----------------
// T2 LDS XOR-swizzle ((row&7)<<4) with inverse-swizzled gload_lds source; T4 counted vmcnt
// (loads stay in flight across barriers); T5 setprio; raw s_barrier (no implicit drain).
// Schedule per K-tile t (buf=t&1): read A-half0+B frags -> MFMA mh0 -> read A-half1 ->
// lgkm(0)+barrier (buffer free) -> stage K-tile t+2 into buf -> MFMA mh1 -> vmcnt(cnt)+barrier.
// MODE 0: bf16 C (ldc); blocks with col0>=3072 write V transposed to Vt.  MODE 1: fp32 C.
template<int NREP, int MODE>
__global__ __launch_bounds__(512, 2) void k_gemm256(const unsigned short* __restrict__ A,
                                                    const unsigned short* __restrict__ Bt,
                                                    void* __restrict__ Cv,
                                                    unsigned short* __restrict__ Vt,
                                                    int M, int N, int K, int ldc) {
    constexpr int BN  = NREP * 64;     // 256 or 128
    constexpr int BWC = NREP * 16;     // per-wave col span
    constexpr int NLD = 4 + NREP;      // gloads per wave per K-tile
    __shared__ __align__(16) char As[2][32768];
    __shared__ __align__(16) char Bs[2][BN * 128];
    int bid = blockIdx.x;
    int rem = (bid & 7) * 32 + (bid >> 3);      // T1 bijective XCD swizzle (nwg=256)
    int bx = rem & 15, by = rem >> 4;
    int row0 = by * 256, col0 = bx * BN;
    int tid = threadIdx.x, wave = tid >> 6, lane = tid & 63;
    int wr = wave >> 2, wc = wave & 3;
    int g = lane >> 4, r16 = lane & 15;
    const char* Ab = (const char*)A;
    const char* Bb = (const char*)Bt;

    f32x4 acc[8][NREP] = {};

    auto STAGE = [&](int buf, int t) {
        int k0b = t * 128;                       // byte offset into K (64 elems * 2B)
        #pragma unroll
        for (int p = 0; p < 4; ++p) {
            int c = wave * 4 + p;
            int o = c * 1024 + lane * 16;
            int row = o >> 7;
            int colb = (o & 127) ^ ((row & 7) << 4);
            gload16(Ab + (size_t)(row0 + row) * (size_t)(K * 2) + k0b + colb, &As[buf][c * 1024]);
        }
        #pragma unroll
        for (int p = 0; p < NREP; ++p) {
            int c = wave * NREP + p;
            int o = c * 1024 + lane * 16;
            int row = o >> 7;
            int colb = (o & 127) ^ ((row & 7) << 4);
            gload16(Bb + (size_t)(col0 + row) * (size_t)(K * 2) + k0b + colb, &Bs[buf][c * 1024]);
        }
    };

    int nt = K >> 6;
    STAGE(0, 0);
    STAGE(1, 1);
    if constexpr (NREP == 4) asm volatile("s_waitcnt vmcnt(8)" ::: "memory");
    else                     asm volatile("s_waitcnt vmcnt(6)" ::: "memory");
    __builtin_amdgcn_s_barrier();

    for (int t = 0; t < nt; ++t) {
        int buf = t & 1;
        const char* AL = As[buf];
        const char* BL = Bs[buf];
        bf16x8 a0[4][2], a1[4][2], bfr[NREP][2];
        #pragma unroll
        for (int mi = 0; mi < 4; ++mi)
            #pragma unroll
            for (int s = 0; s < 2; ++s) {
                int r = wr*128 + mi*16 + r16;
                int o = r*128 + s*64 + g*16;
                a0[mi][s] = *(const bf16x8*)(AL + (o ^ ((r & 7) << 4)));
            }
        #pragma unroll
        for (int ni = 0; ni < NREP; ++ni)
            #pragma unroll
            for (int s = 0; s < 2; ++s) {
                int r = wc*BWC + ni*16 + r16;
                int o = r*128 + s*64 + g*16;
                bfr[ni][s] = *(const bf16x8*)(BL + (o ^ ((r & 7) << 4)));
            }
        __builtin_amdgcn_s_setprio(1);
        #pragma unroll
        for (int mi = 0; mi < 4; ++mi)
            #pragma unroll
            for (int ni = 0; ni < NREP; ++ni)
                #pragma unroll
                for (int s = 0; s < 2; ++s)
                    acc[mi][ni] = __builtin_amdgcn_mfma_f32_16x16x32_bf16(a0[mi][s], bfr[ni][s], acc[mi][ni], 0, 0, 0);
        __builtin_amdgcn_s_setprio(0);
        #pragma unroll
        for (int mi = 0; mi < 4; ++mi)
            #pragma unroll
            for (int s = 0; s < 2; ++s) {
                int r = wr*128 + 64 + mi*16 + r16;
                int o = r*128 + s*64 + g*16;
                a1[mi][s] = *(const bf16x8*)(AL + (o ^ ((r & 7) << 4)));
            }
        asm volatile("s_waitcnt lgkmcnt(0)" ::: "memory");
        __builtin_amdgcn_sched_barrier(0);
        __builtin_amdgcn_s_barrier();            // barrier A: block-wide done reading buf
        if (t + 2 < nt) STAGE(buf, t + 2);       // overwrite freed buffer (loads fly under MFMA)
        __builtin_amdgcn_sched_barrier(0);
        __builtin_amdgcn_s_setprio(1);
        #pragma unroll
        for (int mi = 0; mi < 4; ++mi)
            #pragma unroll
            for (int ni = 0; ni < NREP; ++ni)
                #pragma unroll
                for (int s = 0; s < 2; ++s)
                    acc[mi+4][ni] = __builtin_amdgcn_mfma_f32_16x16x32_bf16(a1[mi][s], bfr[ni][s], acc[mi+4][ni], 0, 0, 0);
        __builtin_amdgcn_s_setprio(0);
        if (t + 2 < nt) {
            if constexpr (NREP == 4) asm volatile("s_waitcnt vmcnt(8)" ::: "memory");
            else                     asm volatile("s_waitcnt vmcnt(6)" ::: "memory");
        } else {
            asm volatile("s_waitcnt vmcnt(0)" ::: "memory");
        }
        __builtin_amdgcn_s_barrier();            // barrier B: K-tile t+1 data landed everywhere
    }

    // epilogue
    #pragma unroll
    for (int mi = 0; mi < 8; ++mi)
        #pragma unroll
        for (int ni = 0; ni < NREP; ++ni) {
            if (MODE == 0 && col0 >= 3072) {
                int vcol = col0 + wc*BWC + ni*16 + r16 - 3072;
                int d = vcol & 127, kh = vcol >> 7;
                int row = row0 + wr*128 + mi*16 + g*4;
                int b = row >> 11, s = row & (SEQ-1);
                u16x4 pk;
                #pragma unroll
                for (int rr = 0; rr < 4; ++rr) pk[rr] = f2bf(acc[mi][ni][rr]);
                *(u16x4*)&Vt[((size_t)(b*NKV + kh)*HD + d)*SEQ + s] = pk;
            } else {
                #pragma unroll
                for (int rr = 0; rr < 4; ++rr) {
                    int row = row0 + wr*128 + mi*16 + g*4 + rr;
                    int col = col0 + wc*BWC + ni*16 + r16;
                    float v = acc[mi][ni][rr];
                    if (MODE == 1) ((float*)Cv)[(size_t)row*ldc + col] = v;
                    else ((unsigned short*)Cv)[(size_t)row*ldc + col] = f2bf(v);
                }
            }
        }
}

// ---------------- RoPE in place on Q and K columns of the qkv buffer (ld=3072) ----------------
__global__ __launch_bounds__(256) void k_rope(unsigned short* __restrict__ qkv) {
    int tid = blockIdx.x * 256 + threadIdx.x;   // MTOK*(NH+NKV)*64 threads
    int i    = tid & 63;                        // rotation pair index
    int rest = tid >> 6;
    int head = rest % (NH + NKV);
    int tok  = rest / (NH + NKV);
    int pos  = tok & (SEQ - 1);
    size_t base = (size_t)tok * QKLD + head*HD;
    float x1 = bf2f(qkv[base + i]);
    float x2 = bf2f(qkv[base + i + 64]);
    float inv = exp2f(-0.20762050593046014f * (float)i);   // 10000^(-i/64)
    float ang = (float)pos * inv;
    float s, c;
    sincosf(ang, &s, &c);
    qkv[base + i]      = f2bf(x1*c - x2*s);
    qkv[base + i + 64] = f2bf(x2*c + x1*s);
}

// ---------------- causal GQA flash attention, 32x32 MFMA + in-register softmax ----------------
__global__ __launch_bounds__(256, 2) void k_attn(const unsigned short* __restrict__ qkv,
                                                 const unsigned short* __restrict__ Vt,
                                                 unsigned short* __restrict__ attn_out) {
    __shared__ __align__(16) char KsB[2][16384];   // [kv 64][d 128] bf16, 256B rows
    __shared__ __align__(16) char VsB[2][16384];   // [d 128][kv 64] bf16, 128B rows
    int bid = blockIdx.x;
    int xcd = bid & 7, slot = bid >> 3;            // 64 slots per XCD
    int bh  = xcd * 4 + (slot >> 4);               // 4 bh per XCD (L2 locality)
    int xx  = slot & 15;
    int qt  = (slot & 32) ? (15 - xx) : xx;        // complementary qt pairing for causal balance
    int b = bh >> 4, h = bh & 15;
    int kvh = h >> 1;
    int tid = threadIdx.x, wave = tid >> 6, lane = tid & 63;
    int l31 = lane & 31, hi = lane >> 5;
    int q0w = qt * 128 + wave * 32;
    int qg  = q0w + l31;                           // this lane's q row
    const unsigned short* qbase = qkv + (size_t)(b * SEQ) * QKLD;
    const char* kbase = (const char*)(qbase + DIMX + kvh * HD);                  // + row*QKLD*2
    const char* vbase = (const char*)(Vt + ((size_t)(b * NKV + kvh) * HD) * SEQ); // + d*SEQ*2

    // Q B-frags: lane holds Q[qg][d = 16s + 8hi + j]
    bf16x8 qf[8];
    {
        const unsigned short* qrow = qbase + (size_t)qg * QKLD + h * HD;
        #pragma unroll
        for (int s2 = 0; s2 < 8; ++s2)
            qf[s2] = *(const bf16x8*)(qrow + s2*16 + hi*8);
    }

    f32x16 acc[4] = {};                            // O^T: d = 32dt + (r&3)+8(r>>2)+4hi, q = l31
    float mrow = -1e30f, lrow = 0.f;
    const float SC = 0.08838834764831845f * 1.4426950408889634f;  // rsqrt(128)*log2(e)

    auto STAGE = [&](int bsel, int it) {
        int kv0 = it * 64;
        char* KL = KsB[bsel];
        char* VL = VsB[bsel];
        #pragma unroll
        for (int p = 0; p < 4; ++p) {
            int c = wave*4 + p;
            {   // K chunk: LDS[o] = K[o>>8][(o&255) ^ ((row&7)<<4)]
                int row  = c*4 + (lane >> 4);
                int colb = ((lane & 15) * 16) ^ ((row & 7) << 4);
                gload16(kbase + (size_t)(kv0 + row) * (QKLD*2) + colb, KL + c*1024);
            }
            {   // V chunk: LDS[o] = Vt[o>>7][(o&127) ^ ((d&7)<<4)]
                int d    = c*8 + (lane >> 3);
                int colb = ((lane & 7) * 16) ^ ((d & 7) << 4);
                gload16(vbase + (size_t)d * (SEQ*2) + (size_t)kv0*2 + colb, VL + c*1024);
            }
        }
    };

    int nt = 2*qt + 2;
    STAGE(0, 0);
    asm volatile("s_waitcnt vmcnt(0)" ::: "memory");
    __syncthreads();

    for (int it = 0; it < nt; ++it) {
        int bsel = it & 1;
        int kv0 = it * 64;
        if (it + 1 < nt) STAGE((it+1) & 1, it + 1);     // issue next-tile loads (overlap compute)
        if (kv0 <= q0w + 31) {
            const char* KL = KsB[bsel];
            const char* VL = VsB[bsel];
            // ---- S^T = K . Q^T ----
            f32x16 st[2] = {};
            __builtin_amdgcn_s_setprio(1);
            #pragma unroll
            for (int t = 0; t < 2; ++t) {
                int row = t*32 + l31;
                const char* kr = KL + row*256;
                unsigned sw = (unsigned)((row & 7) << 4);
                #pragma unroll
                for (int s2 = 0; s2 < 8; ++s2) {
                    bf16x8 kf = *(const bf16x8*)(kr + (((unsigned)(s2*32 + hi*16)) ^ sw));
                    st[t] = __builtin_amdgcn_mfma_f32_32x32x16_bf16(kf, qf[s2], st[t], 0, 0, 0);
                }
            }
            __builtin_amdgcn_s_setprio(0);
            // ---- scale + causal mask + lane-local max ----
            float mt = -1e30f;
            if (kv0 + 63 <= q0w) {
                #pragma unroll
                for (int t = 0; t < 2; ++t)
                    #pragma unroll
                    for (int r = 0; r < 16; ++r) {
                        float v = st[t][r] * SC;
                        st[t][r] = v; mt = fmaxf(mt, v);
                    }
            } else {
                #pragma unroll
                for (int t = 0; t < 2; ++t)
                    #pragma unroll
                    for (int r = 0; r < 16; ++r) {
                        int kv = kv0 + t*32 + (r & 3) + 8*(r >> 2) + 4*hi;
                        float v = (kv <= qg) ? st[t][r] * SC : -1e30f;
                        st[t][r] = v; mt = fmaxf(mt, v);
                    }
            }
            mt = fmaxf(mt, __shfl_xor(mt, 32, 64));
            // ---- defer-max online softmax (T13, THR=8) ----
            if (!__all(mt - mrow <= 8.0f)) {
                float mn = fmaxf(mrow, mt);
                float corr = exp2f(mrow - mn);
                mrow = mn;
                lrow *= corr;
                #pragma unroll
                for (int dt = 0; dt < 4; ++dt)
                    #pragma unroll
                    for (int r = 0; r < 16; ++r) acc[dt][r] *= corr;
            }
            float rs = 0.f;
            #pragma unroll
            for (int t = 0; t < 2; ++t)
                #pragma unroll
                for (int r = 0; r < 16; ++r) {
                    float p = exp2f(st[t][r] - mrow);
                    st[t][r] = p; rs += p;
                }
            rs += __shfl_xor(rs, 32, 64);
            lrow += rs;
            // ---- P in-register (cvt_pk + permlane32_swap) + PV ----
            #pragma unroll
            for (int t = 0; t < 2; ++t)
                #pragma unroll
                for (int ks = 0; ks < 2; ++ks) {
                    int rb = ks * 8;
                    float p0 = st[t][rb+0], p1 = st[t][rb+1], p2 = st[t][rb+2], p3 = st[t][rb+3];
                    float p4 = st[t][rb+4], p5 = st[t][rb+5], p6 = st[t][rb+6], p7 = st[t][rb+7];
                    unsigned w0, w1, w2, w3;
                    asm("v_cvt_pk_bf16_f32 %0, %1, %2" : "=v"(w0) : "v"(p0), "v"(p1));
                    asm("v_cvt_pk_bf16_f32 %0, %1, %2" : "=v"(w1) : "v"(p2), "v"(p3));
                    asm("v_cvt_pk_bf16_f32 %0, %1, %2" : "=v"(w2) : "v"(p4), "v"(p5));
                    asm("v_cvt_pk_bf16_f32 %0, %1, %2" : "=v"(w3) : "v"(p6), "v"(p7));
                    asm("v_permlane32_swap_b32 %0, %1" : "+v"(w0), "+v"(w2));
                    asm("v_permlane32_swap_b32 %0, %1" : "+v"(w1), "+v"(w3));
                    u32x4 pu = {w0, w1, w2, w3};
                    bf16x8 pfrag = __builtin_bit_cast(bf16x8, pu);
                    int ks4 = t*2 + ks;
                    __builtin_amdgcn_s_setprio(1);
                    #pragma unroll
                    for (int dt = 0; dt < 4; ++dt) {
                        int d = dt*32 + l31;
                        bf16x8 vf = *(const bf16x8*)(VL + d*128 +
                                     (((unsigned)(ks4*32 + hi*16)) ^ ((unsigned)((d & 7) << 4))));
                        acc[dt] = __builtin_amdgcn_mfma_f32_32x32x16_bf16(vf, pfrag, acc[dt], 0, 0, 0);
                    }
                    __builtin_amdgcn_s_setprio(0);
                }
        }
        asm volatile("s_waitcnt vmcnt(0)" ::: "memory");
        __syncthreads();
    }

    // ---- epilogue: normalize (lane-local), write bf16, 8B stores ----
    float inv = 1.0f / lrow;
    #pragma unroll
    for (int dt = 0; dt < 4; ++dt)
        #pragma unroll
        for (int qd = 0; qd < 4; ++qd) {
            u16x4 o4;
            #pragma unroll
            for (int j = 0; j < 4; ++j) o4[j] = f2bf(acc[dt][qd*4 + j] * inv);
            int d0 = dt*32 + qd*8 + hi*4;
            *(u16x4*)&attn_out[(size_t)(b*SEQ + qg)*DIMX + h*HD + d0] = o4;
        }
}

extern "C" void kernel_launch(void* const* d_in, const int* in_sizes, int n_in,
                              void* d_out, int out_size, void* d_ws, size_t ws_size,
                              hipStream_t stream) {
    const float* x  = (const float*)d_in[0];
    const float* Wq = (const float*)d_in[1];
    const float* Wk = (const float*)d_in[2];
    const float* Wv = (const float*)d_in[3];
    const float* Wo = (const float*)d_in[4];

    // ws layout (all u16), total 92.3 MB
    unsigned short* xb   = (unsigned short*)d_ws;                 // 4096x2048
    unsigned short* Wtq  = xb  + (size_t)MTOK*DIMX;               // 4096x2048 (QKV weights, NxK)
    unsigned short* Wto  = Wtq + (size_t)NQKV*DIMX;               // 2048x2048 (Wo^T)
    unsigned short* qkv  = Wto + (size_t)DIMX*DIMX;               // 4096x3072 (Q|K, ld 3072)
    unsigned short* aout = qkv + (size_t)MTOK*QKLD;               // 4096x2048
    unsigned short* Vt   = aout + (size_t)MTOK*DIMX;              // [2][8][128][2048]

    k_convert<<<(MTOK*DIMX/8 + 255)/256, 256, 0, stream>>>(x, xb, MTOK*DIMX/8);

    dim3 tg32(DIMX/64, DIMX/64);
    dim3 tg16(1024/64, DIMX/64);
    k_transpose<<<tg32, 256, 0, stream>>>(Wq, Wtq,                         DIMX, DIMX);
    k_transpose<<<tg16, 256, 0, stream>>>(Wk, Wtq + (size_t)2048*DIMX,     DIMX, 1024);
    k_transpose<<<tg16, 256, 0, stream>>>(Wv, Wtq + (size_t)3072*DIMX,     DIMX, 1024);
    k_transpose<<<tg32, 256, 0, stream>>>(Wo, Wto,                         DIMX, DIMX);

    // GEMM1: 4096x4096x2048, 256x256 tiles -> 256 blocks
    k_gemm256<4, 0><<<256, 512, 0, stream>>>(xb, Wtq, qkv, Vt, MTOK, NQKV, DIMX, QKLD);

    k_rope<<<(MTOK*(NH+NKV)*64)/256, 256, 0, stream>>>(qkv);

    k_attn<<<512, 256, 0, stream>>>(qkv, Vt, aout);

    // GEMM2: 4096x2048x2048, 256x128 tiles -> 256 blocks
    k_gemm256<2, 1><<<256, 512, 0, stream>>>(aout, Wto, (float*)d_out, nullptr, MTOK, DIMX, DIMX, DIMX);
}